// Round 10
// baseline (72.895 us; speedup 1.0000x reference)
//
#include <hip/hip_runtime.h>
#include <cmath>

// RMSDLoss (batched Kabsch RMSD, mean over batch) — fully fused single pass.
// R6/R8 both 26.6us with different burst shapes -> MLP no longer binding;
// remaining removable cost = mean kernel + launch gap (~4us). R10 fuses the
// mean via HIERARCHICAL arrival counters (R3-R5: 2048 same-address atomics
// cost ~15-20us -> avoid): 32 level-1 counters (one per 64 blocks, each on its
// own 128B line, <=64 serialized adds each, hidden under other blocks' tails),
// 1 level-2 counter (32 adds). The grid-closer block reads all rms[] (8KB)
// and writes the mean. Agent-scope atomics + threadfence per G16 (pattern
// validated in R7). Main loop = R8's proven 2x6-load burst + sched_barrier.
// fp32 solve (absmax 0.0 across R2-R9).

constexpr int BLOCK = 256;
constexpr int NWAVE = BLOCK / 64;
constexpr int NS = 17;

template<int N>
__global__ __launch_bounds__(BLOCK, 8) void rmsd_kernel(
    const float* __restrict__ yp,   // [B,N,3] coords (y_prime)
    const float* __restrict__ yr,   // [B,N,3] reference (y)
    float* __restrict__ rms,        // [B] scratch
    int*   __restrict__ cnt1,       // 32 counters, stride 32 ints (128B lines)
    int*   __restrict__ cnt2,       // 1 counter
    float* __restrict__ out,        // [1]
    int Btot, float invB)
{
    static_assert(N == BLOCK * 8, "one thread = 8 atoms = 6 float4");
    const int b   = blockIdx.x;
    const int tid = threadIdx.x;
    const size_t row = (size_t)b * (size_t)N * 3u;
    const float4* p4 = (const float4*)(yp + row) + tid * 6;
    const float4* q4 = (const float4*)(yr + row) + tid * 6;

    float s1x=0.f,s1y=0.f,s1z=0.f, s2x=0.f,s2y=0.f,s2z=0.f, sq1=0.f,sq2=0.f;
    float c00=0.f,c01=0.f,c02=0.f,c10=0.f,c11=0.f,c12=0.f,c20=0.f,c21=0.f,c22=0.f;

    auto accum4 = [&](const float4&a0,const float4&a1,const float4&a2,
                      const float4&b0,const float4&b1,const float4&b2){
        float px[4]={a0.x,a0.w,a1.z,a2.y};
        float py[4]={a0.y,a1.x,a1.w,a2.z};
        float pz[4]={a0.z,a1.y,a2.x,a2.w};
        float qx[4]={b0.x,b0.w,b1.z,b2.y};
        float qy[4]={b0.y,b1.x,b1.w,b2.z};
        float qz[4]={b0.z,b1.y,b2.x,b2.w};
        #pragma unroll
        for (int k=0;k<4;k++){
            s1x+=px[k]; s1y+=py[k]; s1z+=pz[k];
            s2x+=qx[k]; s2y+=qy[k]; s2z+=qz[k];
            sq1 = fmaf(px[k],px[k], fmaf(py[k],py[k], fmaf(pz[k],pz[k], sq1)));
            sq2 = fmaf(qx[k],qx[k], fmaf(qy[k],qy[k], fmaf(qz[k],qz[k], sq2)));
            c00=fmaf(px[k],qx[k],c00); c01=fmaf(px[k],qy[k],c01); c02=fmaf(px[k],qz[k],c02);
            c10=fmaf(py[k],qx[k],c10); c11=fmaf(py[k],qy[k],c11); c12=fmaf(py[k],qz[k],c12);
            c20=fmaf(pz[k],qx[k],c20); c21=fmaf(pz[k],qy[k],c21); c22=fmaf(pz[k],qz[k],c22);
        }
    };

    // Phase A: 6-load burst (atoms 0..3), all issued before consumption.
    {
        const float4 P0=p4[0], P1=p4[1], P2=p4[2];
        const float4 Q0=q4[0], Q1=q4[1], Q2=q4[2];
        __builtin_amdgcn_sched_barrier(0);
        accum4(P0,P1,P2, Q0,Q1,Q2);
    }
    // Phase B: 6-load burst (atoms 4..7).
    {
        const float4 P3=p4[3], P4=p4[4], P5=p4[5];
        const float4 Q3=q4[3], Q4=q4[4], Q5=q4[5];
        __builtin_amdgcn_sched_barrier(0);
        accum4(P3,P4,P5, Q3,Q4,Q5);
    }

    // Block reduction of the 17 sums.
    float vals[NS] = {s1x,s1y,s1z,s2x,s2y,s2z,sq1,sq2,
                      c00,c01,c02,c10,c11,c12,c20,c21,c22};
    __shared__ float sred[NWAVE][NS];
    const int wave = tid >> 6, lane = tid & 63;
    #pragma unroll
    for (int i = 0; i < NS; ++i) {
        float v = vals[i];
        #pragma unroll
        for (int off = 32; off > 0; off >>= 1) v += __shfl_down(v, off, 64);
        if (lane == 0) sred[wave][i] = v;
    }
    __syncthreads();

    __shared__ int sflag;
    if (tid == 0) {
        float t[NS];
        #pragma unroll
        for (int i = 0; i < NS; ++i) {
            float s = 0.f;
            #pragma unroll
            for (int w = 0; w < NWAVE; ++w) s += sred[w][i];
            t[i] = s;
        }
        const float fn = (float)N;
        const float m1x=t[0]/fn, m1y=t[1]/fn, m1z=t[2]/fn;
        const float m2x=t[3]/fn, m2y=t[4]/fn, m2z=t[5]/fn;
        const float E0 = (t[6] - fn*(m1x*m1x+m1y*m1y+m1z*m1z))
                       + (t[7] - fn*(m2x*m2x+m2y*m2y+m2z*m2z));
        const float A00=t[8] -fn*m1x*m2x, A01=t[9] -fn*m1x*m2y, A02=t[10]-fn*m1x*m2z;
        const float A10=t[11]-fn*m1y*m2x, A11=t[12]-fn*m1y*m2y, A12=t[13]-fn*m1y*m2z;
        const float A20=t[14]-fn*m1z*m2x, A21=t[15]-fn*m1z*m2y, A22=t[16]-fn*m1z*m2z;

        const float det = A00*(A11*A22-A12*A21)
                        - A01*(A10*A22-A12*A20)
                        + A02*(A10*A21-A11*A20);

        // G = A^T A (symmetric PSD); analytic eigenvalues (fp32)
        const float G00 = A00*A00+A10*A10+A20*A20;
        const float G01 = A00*A01+A10*A11+A20*A21;
        const float G02 = A00*A02+A10*A12+A20*A22;
        const float G11 = A01*A01+A11*A11+A21*A21;
        const float G12 = A01*A02+A11*A12+A21*A22;
        const float G22 = A02*A02+A12*A12+A22*A22;

        const float q  = (G00+G11+G22)*(1.f/3.f);
        const float p1 = G01*G01 + G02*G02 + G12*G12;
        const float p2 = (G00-q)*(G00-q)+(G11-q)*(G11-q)+(G22-q)*(G22-q) + 2.f*p1;
        const float p  = sqrtf(p2*(1.f/6.f));
        float e1, e2, e3;
        if (p < 1e-20f) {
            e1 = e2 = e3 = q;
        } else {
            const float ip = 1.f/p;
            const float C00=(G00-q)*ip, C01=G01*ip, C02=G02*ip;
            const float C11=(G11-q)*ip, C12=G12*ip, C22=(G22-q)*ip;
            float detC = C00*(C11*C22-C12*C12)
                       - C01*(C01*C22-C12*C02)
                       + C02*(C01*C12-C11*C02);
            float rr = fminf(1.f, fmaxf(-1.f, 0.5f*detC));
            const float phi = acosf(rr)*(1.f/3.f);
            e1 = q + 2.f*p*cosf(phi);
            e3 = q + 2.f*p*cosf(phi + 2.0943951023931953f);  // +2*pi/3
            e2 = 3.f*q - e1 - e3;
        }
        const float sv0 = sqrtf(fmaxf(e1,0.f));
        const float sv1 = sqrtf(fmaxf(e2,0.f));
        const float sv2 = sqrtf(fmaxf(e3,0.f));
        const float trs = sv0 + sv1 + ((det >= 0.f) ? sv2 : -sv2);
        const float msd = fmaxf(0.f, (E0 - 2.f*trs)/fn);
        __hip_atomic_store(&rms[b], sqrtf(msd),
                           __ATOMIC_RELAXED, __HIP_MEMORY_SCOPE_AGENT);
        __threadfence();                       // release rms before arrival

        // Hierarchical arrival: level-1 bucket of 64 blocks (own 128B line).
        const int g   = b >> 6;
        const int bsz = min(64, Btot - (g << 6));
        int flag = 0;
        if (atomicAdd(&cnt1[g * 32], 1) == bsz - 1) {
            const int nbuckets = (Btot + 63) >> 6;
            if (atomicAdd(cnt2, 1) == nbuckets - 1) flag = 1;
        }
        sflag = flag;
    }
    __syncthreads();

    // Grid-closer block computes the mean (all rms[] guaranteed written).
    if (sflag) {
        __threadfence();                       // acquire
        float acc = 0.f;
        for (int i = tid; i < Btot; i += BLOCK)
            acc += __hip_atomic_load(&rms[i],
                                     __ATOMIC_RELAXED, __HIP_MEMORY_SCOPE_AGENT);
        #pragma unroll
        for (int off = 32; off > 0; off >>= 1) acc += __shfl_down(acc, off, 64);
        __shared__ float sred2[NWAVE];
        if (lane == 0) sred2[wave] = acc;
        __syncthreads();
        if (tid == 0) {
            float tot = 0.f;
            #pragma unroll
            for (int w = 0; w < NWAVE; ++w) tot += sred2[w];
            out[0] = tot * invB;
        }
    }
}

extern "C" void kernel_launch(void* const* d_in, const int* in_sizes, int n_in,
                              void* d_out, int out_size, void* d_ws, size_t ws_size,
                              hipStream_t stream) {
    const float* yp = (const float*)d_in[0];   // y_prime [B,N,3] f32
    const float* yr = (const float*)d_in[1];   // y       [B,N,3] f32
    const int N = 2048;
    const int B = in_sizes[0] / (N * 3);

    // d_ws layout: [0,4096) cnt1 (32 counters, 128B apart); [4096,4100) cnt2;
    // [8192, 8192+4B) rms array.
    int*   cnt1 = (int*)d_ws;
    int*   cnt2 = (int*)((char*)d_ws + 4096);
    float* rms  = (float*)((char*)d_ws + 8192);

    hipMemsetAsync(d_ws, 0, 4352, stream);     // zero arrival counters
    rmsd_kernel<2048><<<B, BLOCK, 0, stream>>>(
        yp, yr, rms, cnt1, cnt2, (float*)d_out, B, 1.0f/(float)B);
}

// Round 11
// 30.755 us; speedup vs baseline: 2.3702x; 2.3702x over previous
//
#include <hip/hip_runtime.h>
#include <cmath>

// RMSDLoss (batched Kabsch RMSD, mean over batch).
// R10 lesson: per-block device-scope fences for a fused mean wreck the memory
// system (2048 L2 writeback/invalidates; 26.6 -> 72.9us). Keep 2-kernel split.
// R11: attack the one-shot duty-cycle hole. Each block handles TWO rows,
// pipelined: row1's phase-A loads are issued BEFORE row0's reduce+solve, so
// 6KB/wave stays in flight under the epilogue instead of draining to zero.
// Grid 1024, __launch_bounds__(256,4): VGPR cap 128 so regalloc can keep both
// buffers live (R7 lesson: 84<96 broke the pipeline). sched_barrier(0) pins
// issue clusters (R6 lever). fp32 solve (absmax 0.0 across R2-R10).

constexpr int BLOCK = 256;
constexpr int NWAVE = BLOCK / 64;
constexpr int NS = 17;

template<int N>
__global__ __launch_bounds__(BLOCK, 4) void rmsd_kernel(
    const float* __restrict__ yp,   // [B,N,3] coords (y_prime)
    const float* __restrict__ yr,   // [B,N,3] reference (y)
    float* __restrict__ rms_out)    // [B]
{
    static_assert(N == BLOCK * 8, "one thread = 8 atoms/row = 6 float4/row");
    const int b   = blockIdx.x;          // handles rows 2b and 2b+1
    const int tid = threadIdx.x;
    const int wave = tid >> 6, lane = tid & 63;
    constexpr int ROWF4 = N * 3 / 4;     // float4 per row per tensor

    const float4* p0 = (const float4*)(yp + (size_t)(2*b) * N * 3) + tid * 6;
    const float4* q0 = (const float4*)(yr + (size_t)(2*b) * N * 3) + tid * 6;

    float s1x=0.f,s1y=0.f,s1z=0.f, s2x=0.f,s2y=0.f,s2z=0.f, sq1=0.f,sq2=0.f;
    float c00=0.f,c01=0.f,c02=0.f,c10=0.f,c11=0.f,c12=0.f,c20=0.f,c21=0.f,c22=0.f;

    auto accum4 = [&](const float4&a0,const float4&a1,const float4&a2,
                      const float4&b0,const float4&b1,const float4&b2){
        float px[4]={a0.x,a0.w,a1.z,a2.y};
        float py[4]={a0.y,a1.x,a1.w,a2.z};
        float pz[4]={a0.z,a1.y,a2.x,a2.w};
        float qx[4]={b0.x,b0.w,b1.z,b2.y};
        float qy[4]={b0.y,b1.x,b1.w,b2.z};
        float qz[4]={b0.z,b1.y,b2.x,b2.w};
        #pragma unroll
        for (int k=0;k<4;k++){
            s1x+=px[k]; s1y+=py[k]; s1z+=pz[k];
            s2x+=qx[k]; s2y+=qy[k]; s2z+=qz[k];
            sq1 = fmaf(px[k],px[k], fmaf(py[k],py[k], fmaf(pz[k],pz[k], sq1)));
            sq2 = fmaf(qx[k],qx[k], fmaf(qy[k],qy[k], fmaf(qz[k],qz[k], sq2)));
            c00=fmaf(px[k],qx[k],c00); c01=fmaf(px[k],qy[k],c01); c02=fmaf(px[k],qz[k],c02);
            c10=fmaf(py[k],qx[k],c10); c11=fmaf(py[k],qy[k],c11); c12=fmaf(py[k],qz[k],c12);
            c20=fmaf(pz[k],qx[k],c20); c21=fmaf(pz[k],qy[k],c21); c22=fmaf(pz[k],qz[k],c22);
        }
    };

    __shared__ float sred[NWAVE][NS];

    // Reduce the 17 sums across the block, solve on thread 0, store rms[row],
    // and reset the accumulators. While thread 0 solves, the other waves wait
    // at the trailing barrier -- with the NEXT row's loads already in flight.
    auto reduce_solve = [&](int row){
        float vals[NS] = {s1x,s1y,s1z,s2x,s2y,s2z,sq1,sq2,
                          c00,c01,c02,c10,c11,c12,c20,c21,c22};
        #pragma unroll
        for (int i = 0; i < NS; ++i) {
            float v = vals[i];
            #pragma unroll
            for (int off = 32; off > 0; off >>= 1) v += __shfl_down(v, off, 64);
            vals[i] = v;
        }
        __syncthreads();                 // sred free from previous use
        if (lane == 0) {
            #pragma unroll
            for (int i = 0; i < NS; ++i) sred[wave][i] = vals[i];
        }
        __syncthreads();
        if (tid == 0) {
            float t[NS];
            #pragma unroll
            for (int i = 0; i < NS; ++i) {
                float s = 0.f;
                #pragma unroll
                for (int w = 0; w < NWAVE; ++w) s += sred[w][i];
                t[i] = s;
            }
            const float fn = (float)N;
            const float m1x=t[0]/fn, m1y=t[1]/fn, m1z=t[2]/fn;
            const float m2x=t[3]/fn, m2y=t[4]/fn, m2z=t[5]/fn;
            const float E0 = (t[6] - fn*(m1x*m1x+m1y*m1y+m1z*m1z))
                           + (t[7] - fn*(m2x*m2x+m2y*m2y+m2z*m2z));
            const float A00=t[8] -fn*m1x*m2x, A01=t[9] -fn*m1x*m2y, A02=t[10]-fn*m1x*m2z;
            const float A10=t[11]-fn*m1y*m2x, A11=t[12]-fn*m1y*m2y, A12=t[13]-fn*m1y*m2z;
            const float A20=t[14]-fn*m1z*m2x, A21=t[15]-fn*m1z*m2y, A22=t[16]-fn*m1z*m2z;

            const float det = A00*(A11*A22-A12*A21)
                            - A01*(A10*A22-A12*A20)
                            + A02*(A10*A21-A11*A20);

            const float G00 = A00*A00+A10*A10+A20*A20;
            const float G01 = A00*A01+A10*A11+A20*A21;
            const float G02 = A00*A02+A10*A12+A20*A22;
            const float G11 = A01*A01+A11*A11+A21*A21;
            const float G12 = A01*A02+A11*A12+A21*A22;
            const float G22 = A02*A02+A12*A12+A22*A22;

            const float q  = (G00+G11+G22)*(1.f/3.f);
            const float p1 = G01*G01 + G02*G02 + G12*G12;
            const float p2 = (G00-q)*(G00-q)+(G11-q)*(G11-q)+(G22-q)*(G22-q) + 2.f*p1;
            const float p  = sqrtf(p2*(1.f/6.f));
            float e1, e2, e3;
            if (p < 1e-20f) {
                e1 = e2 = e3 = q;
            } else {
                const float ip = 1.f/p;
                const float C00=(G00-q)*ip, C01=G01*ip, C02=G02*ip;
                const float C11=(G11-q)*ip, C12=G12*ip, C22=(G22-q)*ip;
                float detC = C00*(C11*C22-C12*C12)
                           - C01*(C01*C22-C12*C02)
                           + C02*(C01*C12-C11*C02);
                float rr = fminf(1.f, fmaxf(-1.f, 0.5f*detC));
                const float phi = acosf(rr)*(1.f/3.f);
                e1 = q + 2.f*p*cosf(phi);
                e3 = q + 2.f*p*cosf(phi + 2.0943951023931953f);  // +2*pi/3
                e2 = 3.f*q - e1 - e3;
            }
            const float sv0 = sqrtf(fmaxf(e1,0.f));
            const float sv1 = sqrtf(fmaxf(e2,0.f));
            const float sv2 = sqrtf(fmaxf(e3,0.f));
            const float trs = sv0 + sv1 + ((det >= 0.f) ? sv2 : -sv2);
            const float msd = fmaxf(0.f, (E0 - 2.f*trs)/fn);
            rms_out[row] = sqrtf(msd);
        }
        s1x=s1y=s1z=s2x=s2y=s2z=sq1=sq2=0.f;
        c00=c01=c02=c10=c11=c12=c20=c21=c22=0.f;
    };

    // ---- pipelined 2-row schedule ----
    // Row 0 full burst (12 loads).
    float4 Pa0=p0[0], Pa1=p0[1], Pa2=p0[2];
    float4 Qa0=q0[0], Qa1=q0[1], Qa2=q0[2];
    float4 Pb0=p0[3], Pb1=p0[4], Pb2=p0[5];
    float4 Qb0=q0[3], Qb1=q0[4], Qb2=q0[5];
    __builtin_amdgcn_sched_barrier(0);

    accum4(Pa0,Pa1,Pa2, Qa0,Qa1,Qa2);              // consume A0
    __builtin_amdgcn_sched_barrier(0);

    // Issue row 1 phase A while B0 is still unconsumed / in regs.
    Pa0=p0[ROWF4+0]; Pa1=p0[ROWF4+1]; Pa2=p0[ROWF4+2];
    Qa0=q0[ROWF4+0]; Qa1=q0[ROWF4+1]; Qa2=q0[ROWF4+2];
    __builtin_amdgcn_sched_barrier(0);

    accum4(Pb0,Pb1,Pb2, Qb0,Qb1,Qb2);              // consume B0
    __builtin_amdgcn_sched_barrier(0);

    reduce_solve(2*b);                             // row-0 epilogue; A1 in flight

    // Issue row 1 phase B, then consume A1, B1.
    Pb0=p0[ROWF4+3]; Pb1=p0[ROWF4+4]; Pb2=p0[ROWF4+5];
    Qb0=q0[ROWF4+3]; Qb1=q0[ROWF4+4]; Qb2=q0[ROWF4+5];
    __builtin_amdgcn_sched_barrier(0);

    accum4(Pa0,Pa1,Pa2, Qa0,Qa1,Qa2);              // consume A1
    __builtin_amdgcn_sched_barrier(0);
    accum4(Pb0,Pb1,Pb2, Qb0,Qb1,Qb2);              // consume B1

    reduce_solve(2*b + 1);                         // row-1 epilogue
}

__global__ __launch_bounds__(BLOCK) void mean_kernel(
    const float* __restrict__ rms, float* __restrict__ out, int B)
{
    const int tid = threadIdx.x;
    const float4* r4 = (const float4*)rms;
    float s = 0.f;
    for (int i = tid; i < B/4; i += BLOCK) {
        float4 v = r4[i];
        s += (v.x + v.y) + (v.z + v.w);
    }
    #pragma unroll
    for (int off = 32; off > 0; off >>= 1) s += __shfl_down(s, off, 64);
    __shared__ float sred[NWAVE];
    const int wave = tid >> 6, lane = tid & 63;
    if (lane == 0) sred[wave] = s;
    __syncthreads();
    if (tid == 0) {
        float tot = 0.f;
        #pragma unroll
        for (int w = 0; w < NWAVE; ++w) tot += sred[w];
        out[0] = tot / (float)B;
    }
}

extern "C" void kernel_launch(void* const* d_in, const int* in_sizes, int n_in,
                              void* d_out, int out_size, void* d_ws, size_t ws_size,
                              hipStream_t stream) {
    const float* yp = (const float*)d_in[0];   // y_prime [B,N,3] f32
    const float* yr = (const float*)d_in[1];   // y       [B,N,3] f32
    const int N = 2048;
    const int B = in_sizes[0] / (N * 3);
    float* rms_ws = (float*)d_ws;              // B floats

    rmsd_kernel<2048><<<B/2, BLOCK, 0, stream>>>(yp, yr, rms_ws);
    mean_kernel<<<1, BLOCK, 0, stream>>>(rms_ws, (float*)d_out, B);
}